// Round 2
// baseline (8946.013 us; speedup 1.0000x reference)
//
#include <hip/hip_runtime.h>
#include <hip/hip_bf16.h>

// Problem constants
#define LNUM 4
#define EDIM 1024
#define HID 1024
#define NH 16
#define HD 64
#define VOC 32000
#define SEQ 1024
#define BATCH 2
#define NTOK (BATCH * SEQ)   // 2048
#define HCHUNK 8             // heads per attention chunk (sc buffer = 32 MB)

// -----------------------------------------------------------------------------
// Generic tiled fp32 GEMM:
//   C[m,n] = scale * sum_k A(m,k)*B(k,n) + bias[n] + Cadd[m,n], opt relu.
// A(m,k) = TRA ? A[k*lda+m] : A[m*lda+k];  B(k,n) = TRB ? B[n*ldb+k] : B[k*ldb+n]
// Batched over blockIdx.z with element strides sA/sB/sC.
// Requires M%64==0, N%64==0, K%16==0 (all shapes here satisfy this).
// -----------------------------------------------------------------------------
template <bool TRA, bool TRB>
__global__ __launch_bounds__(256) void gemm_k(
    const float* __restrict__ Ag, const float* __restrict__ Bg, float* __restrict__ Cg,
    int M, int N, int K, int lda, int ldb, int ldc,
    long sA, long sB, long sC, float scale,
    const float* __restrict__ bias, const float* __restrict__ Cadd, int relu)
{
    const float* A = Ag + (long)blockIdx.z * sA;
    const float* B = Bg + (long)blockIdx.z * sB;
    float* C = Cg + (long)blockIdx.z * sC;

    __shared__ float As[16][68];  // [k][m], padded
    __shared__ float Bs[16][68];  // [k][n], padded

    const int tid = threadIdx.x;
    const int tx = tid & 15;   // n-quad
    const int ty = tid >> 4;   // m-quad
    const int bm = blockIdx.y * 64;
    const int bn = blockIdx.x * 64;

    float acc[4][4] = {};

    for (int k0 = 0; k0 < K; k0 += 16) {
        #pragma unroll
        for (int i = 0; i < 4; ++i) {
            int idx = tid + i * 256;
            int m, k;
            if (TRA) { m = idx & 63; k = idx >> 6; }
            else     { k = idx & 15; m = idx >> 4; }
            int gm = bm + m, gk = k0 + k;
            As[k][m] = TRA ? A[(long)gk * lda + gm] : A[(long)gm * lda + gk];
        }
        #pragma unroll
        for (int i = 0; i < 4; ++i) {
            int idx = tid + i * 256;
            int n, k;
            if (TRB) { k = idx & 15; n = idx >> 4; }
            else     { n = idx & 63; k = idx >> 6; }
            int gk = k0 + k, gn = bn + n;
            Bs[k][n] = TRB ? B[(long)gn * ldb + gk] : B[(long)gk * ldb + gn];
        }
        __syncthreads();
        #pragma unroll
        for (int kk = 0; kk < 16; ++kk) {
            float a[4], b[4];
            #pragma unroll
            for (int i = 0; i < 4; ++i) a[i] = As[kk][ty * 4 + i];
            #pragma unroll
            for (int j = 0; j < 4; ++j) b[j] = Bs[kk][tx * 4 + j];
            #pragma unroll
            for (int i = 0; i < 4; ++i)
                #pragma unroll
                for (int j = 0; j < 4; ++j) acc[i][j] += a[i] * b[j];
        }
        __syncthreads();
    }

    #pragma unroll
    for (int i = 0; i < 4; ++i) {
        int m = bm + ty * 4 + i;
        #pragma unroll
        for (int j = 0; j < 4; ++j) {
            int n = bn + tx * 4 + j;
            float v = acc[i][j] * scale;
            if (bias) v += bias[n];
            if (Cadd) v += Cadd[(long)m * ldc + n];
            if (relu) v = fmaxf(v, 0.0f);
            C[(long)m * ldc + n] = v;
        }
    }
}

// x[b,s,e] = tok_embed[tokens[b,s], e] + pos_embed[s, e]
__global__ __launch_bounds__(256) void embed_k(
    const int* __restrict__ tokens, const float* __restrict__ tok_embed,
    const float* __restrict__ pos_embed, float* __restrict__ x)
{
    long i = (long)blockIdx.x * 256 + threadIdx.x;  // over NTOK*EDIM
    long se = i / EDIM;
    int e = (int)(i % EDIM);
    int s = (int)(se % SEQ);
    int t = tokens[se];
    x[i] = tok_embed[(long)t * EDIM + e] + pos_embed[(long)s * EDIM + e];
}

// in-place row softmax over last axis (ncol columns per row)
__global__ __launch_bounds__(256) void softmax_rows(float* __restrict__ x, int ncol)
{
    long row = blockIdx.x;
    float* p = x + row * (long)ncol;
    int tid = threadIdx.x;
    __shared__ float red[256];

    float lmax = -1e30f;
    for (int c = tid; c < ncol; c += 256) lmax = fmaxf(lmax, p[c]);
    red[tid] = lmax; __syncthreads();
    for (int s = 128; s > 0; s >>= 1) { if (tid < s) red[tid] = fmaxf(red[tid], red[tid + s]); __syncthreads(); }
    float m = red[0]; __syncthreads();

    float lsum = 0.0f;
    for (int c = tid; c < ncol; c += 256) { float e = expf(p[c] - m); p[c] = e; lsum += e; }
    red[tid] = lsum; __syncthreads();
    for (int s = 128; s > 0; s >>= 1) { if (tid < s) red[tid] += red[tid + s]; __syncthreads(); }
    float inv = 1.0f / red[0];
    for (int c = tid; c < ncol; c += 256) p[c] *= inv;
}

// out = rmsnorm(xin (+ add), scale); add may be null
__global__ __launch_bounds__(256) void rmsnorm_k(
    const float* __restrict__ xin, const float* __restrict__ add,
    const float* __restrict__ scale, float* __restrict__ out, int ncol)
{
    long row = blockIdx.x;
    const float* a = xin + row * (long)ncol;
    const float* b = add ? add + row * (long)ncol : nullptr;
    float* o = out + row * (long)ncol;
    int tid = threadIdx.x;
    __shared__ float red[256];

    float ss = 0.0f;
    for (int c = tid; c < ncol; c += 256) { float v = a[c] + (b ? b[c] : 0.0f); ss += v * v; }
    red[tid] = ss; __syncthreads();
    for (int s = 128; s > 0; s >>= 1) { if (tid < s) red[tid] += red[tid + s]; __syncthreads(); }
    float r = rsqrtf(red[0] / (float)ncol + 1e-6f);
    for (int c = tid; c < ncol; c += 256) {
        float v = a[c] + (b ? b[c] : 0.0f);
        o[c] = v * r * scale[c];
    }
}

// in-place log_softmax on fp32 rows
__global__ __launch_bounds__(256) void logsoftmax_k(float* __restrict__ out, int ncol)
{
    long row = blockIdx.x;
    float* p = out + row * (long)ncol;
    int tid = threadIdx.x;
    __shared__ float red[256];

    float lmax = -1e30f;
    for (int c = tid; c < ncol; c += 256) lmax = fmaxf(lmax, p[c]);
    red[tid] = lmax; __syncthreads();
    for (int s = 128; s > 0; s >>= 1) { if (tid < s) red[tid] = fmaxf(red[tid], red[tid + s]); __syncthreads(); }
    float m = red[0]; __syncthreads();

    float lsum = 0.0f;
    for (int c = tid; c < ncol; c += 256) lsum += expf(p[c] - m);
    red[tid] = lsum; __syncthreads();
    for (int s = 128; s > 0; s >>= 1) { if (tid < s) red[tid] += red[tid + s]; __syncthreads(); }
    float lse = m + logf(red[0]);
    for (int c = tid; c < ncol; c += 256) p[c] = p[c] - lse;
}

extern "C" void kernel_launch(void* const* d_in, const int* in_sizes, int n_in,
                              void* d_out, int out_size, void* d_ws, size_t ws_size,
                              hipStream_t stream)
{
    const int*   tokens     = (const int*)d_in[0];
    const float* tok_embed  = (const float*)d_in[1];
    const float* pos_embed  = (const float*)d_in[2];
    const float* Qw_all     = (const float*)d_in[3];
    const float* Kw_all     = (const float*)d_in[4];
    const float* Vw_all     = (const float*)d_in[5];
    const float* Ow_all     = (const float*)d_in[6];
    const float* rms2_all   = (const float*)d_in[7];
    const float* w1_all     = (const float*)d_in[8];
    const float* b1_all     = (const float*)d_in[9];
    const float* w2_all     = (const float*)d_in[10];
    const float* b2_all     = (const float*)d_in[11];
    const float* final_rms  = (const float*)d_in[12];
    const float* w_out      = (const float*)d_in[13];
    const float* b_out      = (const float*)d_in[14];
    float* out = (float*)d_out;

    // fp32 workspace layout — 20M floats = 80 MB total
    float* ws   = (float*)d_ws;
    float* x    = ws;                       // 2M  (NTOK*EDIM)
    float* q    = x   + (long)2 * 1024 * 1024;  // 2M; reused as `rn` after attention
    float* k    = q   + (long)2 * 1024 * 1024;  // 2M
    float* v    = k   + (long)2 * 1024 * 1024;  // 2M
    float* mha  = v   + (long)2 * 1024 * 1024;  // 2M
    float* proj = mha + (long)2 * 1024 * 1024;  // 2M
    float* buf  = proj + (long)2 * 1024 * 1024; // 8M: scores chunk (HCHUNK heads) / FFN hidden
    float* rn   = q;   // alias — q is dead once attention scores are computed

    // 1) embedding
    embed_k<<<(NTOK * (long)EDIM) / 256, 256, 0, stream>>>(tokens, tok_embed, pos_embed, x);

    for (int l = 0; l < LNUM; ++l) {
        const float* Qw  = Qw_all + (long)l * EDIM * HID;
        const float* Kw  = Kw_all + (long)l * EDIM * HID;
        const float* Vw  = Vw_all + (long)l * EDIM * HID;
        const float* Ow  = Ow_all + (long)l * HID * EDIM;
        const float* rs2 = rms2_all + (long)l * EDIM;
        const float* w1  = w1_all + (long)l * EDIM * 4 * EDIM;
        const float* b1  = b1_all + (long)l * 4 * EDIM;
        const float* w2  = w2_all + (long)l * 4 * EDIM * EDIM;
        const float* b2  = b2_all + (long)l * EDIM;

        // q/k/v projections: [2048,1024] = x[2048,1024] @ W[1024,1024]
        gemm_k<false, false><<<dim3(HID / 64, NTOK / 64, 1), 256, 0, stream>>>(
            x, Qw, q, NTOK, HID, EDIM, EDIM, HID, HID, 0, 0, 0, 1.0f, nullptr, nullptr, 0);
        gemm_k<false, false><<<dim3(HID / 64, NTOK / 64, 1), 256, 0, stream>>>(
            x, Kw, k, NTOK, HID, EDIM, EDIM, HID, HID, 0, 0, 0, 1.0f, nullptr, nullptr, 0);
        gemm_k<false, false><<<dim3(HID / 64, NTOK / 64, 1), 256, 0, stream>>>(
            x, Vw, v, NTOK, HID, EDIM, EDIM, HID, HID, 0, 0, 0, 1.0f, nullptr, nullptr, 0);

        for (int b = 0; b < BATCH; ++b) {
            const float* qb = q + (long)b * SEQ * HID;
            const float* kb = k + (long)b * SEQ * HID;
            const float* vb = v + (long)b * SEQ * HID;
            float* mhab = mha + (long)b * SEQ * HID;

            for (int h0 = 0; h0 < NH; h0 += HCHUNK) {
                // scores[h,s,t] = (1/8) * sum_d q[s,(h0+h)*HD+d] * k[t,(h0+h)*HD+d]  (NT, z over h)
                gemm_k<false, true><<<dim3(SEQ / 64, SEQ / 64, HCHUNK), 256, 0, stream>>>(
                    qb + (long)h0 * HD, kb + (long)h0 * HD, buf, SEQ, SEQ, HD, HID, HID, SEQ,
                    HD, HD, (long)SEQ * SEQ, 0.125f, nullptr, nullptr, 0);

                // softmax over t (UNMASKED — bug-faithful)
                softmax_rows<<<HCHUNK * SEQ, 256, 0, stream>>>(buf, SEQ);

                // mha[t,(h0+h)*HD+d] = sum_s attn[h,s,t] * v[s,(h0+h)*HD+d]  (TN, z over h)
                gemm_k<true, false><<<dim3(HD / 64, SEQ / 64, HCHUNK), 256, 0, stream>>>(
                    buf, vb + (long)h0 * HD, mhab + (long)h0 * HD, SEQ, HD, SEQ, SEQ, HID, HID,
                    (long)SEQ * SEQ, HD, HD, 1.0f, nullptr, nullptr, 0);
            }
        }

        // proj = mha @ O
        gemm_k<false, false><<<dim3(EDIM / 64, NTOK / 64, 1), 256, 0, stream>>>(
            mha, Ow, proj, NTOK, EDIM, HID, HID, EDIM, EDIM, 0, 0, 0, 1.0f, nullptr, nullptr, 0);

        // rn = rmsnorm(x + proj) * rs2   (rn aliases q — q is dead now)
        rmsnorm_k<<<NTOK, 256, 0, stream>>>(x, proj, rs2, rn, EDIM);

        // buf = relu(rn @ w1 + b1)   (FFN hidden, 8M floats exactly)
        gemm_k<false, false><<<dim3(4 * EDIM / 64, NTOK / 64, 1), 256, 0, stream>>>(
            rn, w1, buf, NTOK, 4 * EDIM, EDIM, EDIM, 4 * EDIM, 4 * EDIM, 0, 0, 0, 1.0f, b1, nullptr, 1);

        // x = (buf @ w2 + b2) + proj   (bug-faithful: input x NOT re-added; add fused in epilogue)
        gemm_k<false, false><<<dim3(EDIM / 64, NTOK / 64, 1), 256, 0, stream>>>(
            buf, w2, x, NTOK, EDIM, 4 * EDIM, 4 * EDIM, EDIM, EDIM, 0, 0, 0, 1.0f, b2, proj, 0);
    }

    // final rmsnorm -> rn (alias of q)
    rmsnorm_k<<<NTOK, 256, 0, stream>>>(x, nullptr, final_rms, rn, EDIM);

    // logits = rn @ w_out + b_out  -> fp32 directly into d_out
    gemm_k<false, false><<<dim3(VOC / 64, NTOK / 64, 1), 256, 0, stream>>>(
        rn, w_out, out, NTOK, VOC, EDIM, EDIM, VOC, VOC, 0, 0, 0, 1.0f, b_out, nullptr, 0);

    // in-place log_softmax over vocab
    logsoftmax_k<<<NTOK, 256, 0, stream>>>(out, VOC);
}